// Round 1
// baseline (25.708 us; speedup 1.0000x reference)
//
#include <hip/hip_runtime.h>

#define FEAT 41024
#define NF4  (FEAT / 4)   // 10256 float4s per row

// ---------------------------------------------------------------------------
// Kernel 1: the two 256x41024 matvecs + bias + ReLU, fused.
// One block per output row (rows 0..255 -> W_my vs x[:FEAT],
// rows 256..511 -> W_opp vs x[FEAT:]). 256 threads, float4 loads.
// ---------------------------------------------------------------------------
__global__ __launch_bounds__(256) void halfkp_matvec(
    const float* __restrict__ x,
    const float* __restrict__ W_my,  const float* __restrict__ b_my,
    const float* __restrict__ W_opp, const float* __restrict__ b_opp,
    float* __restrict__ h)
{
    const int row = blockIdx.x;
    const int tid = threadIdx.x;

    const float* W;
    const float* xp;
    float bias;
    if (row < 256) {
        W    = W_my + (size_t)row * FEAT;
        bias = b_my[row];
        xp   = x;
    } else {
        W    = W_opp + (size_t)(row - 256) * FEAT;
        bias = b_opp[row - 256];
        xp   = x + FEAT;
    }

    const float4* __restrict__ W4 = (const float4*)W;
    const float4* __restrict__ x4 = (const float4*)xp;

    float acc = 0.f;
    // NF4 = 10256 = 256*40 + 16 -> 40 iters/thread, threads 0..15 do one more.
    for (int i = tid; i < NF4; i += 256) {
        float4 w = W4[i];
        float4 v = x4[i];
        acc += w.x * v.x + w.y * v.y + w.z * v.z + w.w * v.w;
    }

    // wave (64-lane) shuffle reduction
    #pragma unroll
    for (int off = 32; off > 0; off >>= 1)
        acc += __shfl_down(acc, off, 64);

    __shared__ float red[4];
    const int wave = tid >> 6;
    const int lane = tid & 63;
    if (lane == 0) red[wave] = acc;
    __syncthreads();

    if (tid == 0) {
        float s = red[0] + red[1] + red[2] + red[3] + bias;
        h[row] = s > 0.f ? s : 0.f;
    }
}

// ---------------------------------------------------------------------------
// Kernel 2: trailing MLP 512 -> 32 -> 32 -> 1 (relu, relu, linear).
// Single block, 256 threads. All operands tiny (L2-hit).
// ---------------------------------------------------------------------------
__global__ __launch_bounds__(256) void mlp_head(
    const float* __restrict__ h,  // [512] from workspace
    const float* __restrict__ W1, const float* __restrict__ b1,
    const float* __restrict__ W2, const float* __restrict__ b2,
    const float* __restrict__ W3, const float* __restrict__ b3,
    float* __restrict__ out)
{
    __shared__ float hs[512];
    __shared__ float h1[32];
    __shared__ float h2[32];

    const int tid = threadIdx.x;
    hs[tid]       = h[tid];
    hs[tid + 256] = h[tid + 256];
    __syncthreads();

    // layer 1: 32 outputs, 8 threads per output, 64 elems per thread
    const int o = tid >> 3;   // 0..31
    const int j = tid & 7;    // 0..7
    float acc = 0.f;
    const float* __restrict__ w = W1 + o * 512 + j * 64;
    #pragma unroll 8
    for (int k = 0; k < 64; ++k)
        acc += w[k] * hs[j * 64 + k];
    // reduce the 8 consecutive lanes (groups never straddle a wave boundary)
    acc += __shfl_down(acc, 4, 64);
    acc += __shfl_down(acc, 2, 64);
    acc += __shfl_down(acc, 1, 64);
    if (j == 0) {
        float s = acc + b1[o];
        h1[o] = s > 0.f ? s : 0.f;
    }
    __syncthreads();

    // layer 2: 32 outputs, one thread each
    if (tid < 32) {
        float s = b2[tid];
        #pragma unroll 8
        for (int k = 0; k < 32; ++k)
            s += W2[tid * 32 + k] * h1[k];
        h2[tid] = s > 0.f ? s : 0.f;
    }
    __syncthreads();

    // layer 3: scalar output
    if (tid == 0) {
        float s = b3[0];
        #pragma unroll 8
        for (int k = 0; k < 32; ++k)
            s += W3[k] * h2[k];
        out[0] = s;
    }
}

extern "C" void kernel_launch(void* const* d_in, const int* in_sizes, int n_in,
                              void* d_out, int out_size, void* d_ws, size_t ws_size,
                              hipStream_t stream)
{
    const float* x     = (const float*)d_in[0];
    const float* W_my  = (const float*)d_in[1];
    const float* b_my  = (const float*)d_in[2];
    const float* W_opp = (const float*)d_in[3];
    const float* b_opp = (const float*)d_in[4];
    const float* W1    = (const float*)d_in[5];
    const float* b1    = (const float*)d_in[6];
    const float* W2    = (const float*)d_in[7];
    const float* b2    = (const float*)d_in[8];
    const float* W3    = (const float*)d_in[9];
    const float* b3    = (const float*)d_in[10];

    float* out = (float*)d_out;
    float* h   = (float*)d_ws;   // 512 floats of scratch

    halfkp_matvec<<<512, 256, 0, stream>>>(x, W_my, b_my, W_opp, b_opp, h);
    mlp_head<<<1, 256, 0, stream>>>(h, W1, b1, W2, b2, W3, b3, out);
}